// Round 3
// baseline (404.466 us; speedup 1.0000x reference)
//
#include <hip/hip_runtime.h>

// nw_out [N=4, C=19, H=512, W=1024] fp32; output: 1 fp32 scalar.
#define N_IMG 4
#define C_CLS 19
#define HW    (512 * 1024)          // per-channel plane
#define NPIX  (N_IMG * HW)          // 2,097,152 pixels
#define VPIX  (NPIX / 2)            // 1,048,576 float2 pixel-pairs
#define NBLK  (VPIX / 256)          // 4096 blocks
#define IW    0.2f

// Each of the 2*19 accumulators on its own 256 B slot (64 floats) so the
// same-address atomic streams hit 38 distinct L2 channels. Ticket at end.
#define SLOT   64
#define WS_U32 (2 * C_CLS * SLOT + 1)

typedef float f2 __attribute__((ext_vector_type(2)));

__device__ __forceinline__ float* sum_slot(float* ws, int c) { return ws + (size_t)c * SLOT; }
__device__ __forceinline__ float* cnt_slot(float* ws, int c) { return ws + (size_t)(C_CLS + c) * SLOT; }

// ---------------------------------------------------------------------------
// Kernel 1: zero the accumulator slots + ticket (ws is poisoned 0xAA per call)
// ---------------------------------------------------------------------------
__global__ void zero_ws(unsigned int* ws) {
    for (int i = threadIdx.x; i < WS_U32; i += 1024) ws[i] = 0u;
}

// ---------------------------------------------------------------------------
// Kernel 2: one pass; per pixel argmax + sum(prob^2); LDS per-class bins;
// 38 padded global atomics per block; last block (ticket) finalizes.
// 2 pixels/thread keeps live VGPRs ~40 -> 8 waves/SIMD for latency hiding.
// ---------------------------------------------------------------------------
__global__ __launch_bounds__(256) void main_pass(const float* __restrict__ x,
                                                 float* __restrict__ ws,
                                                 unsigned int* __restrict__ ticket,
                                                 float* __restrict__ out) {
    __shared__ float s_sum[C_CLS];
    __shared__ float s_cnt[C_CLS];
    __shared__ unsigned int s_last;
    const int t = threadIdx.x;
    if (t < C_CLS) { s_sum[t] = 0.0f; s_cnt[t] = 0.0f; }
    __syncthreads();

    // float2 pixel-pair index; grid exactly covers VPIX (4096 * 256).
    const int v   = blockIdx.x * 256 + t;
    const int n   = v >> 18;                 // HW/2 = 262144 = 2^18
    const int hw2 = v & (262144 - 1);
    const float* base = x + (size_t)n * C_CLS * HW + (size_t)hw2 * 2;

    // 19 channels x 2 pixels into registers (plain cached dwordx2 loads:
    // input is L3-warm from the harness restore -- do NOT bypass caches).
    f2 val[C_CLS];
#pragma unroll
    for (int c = 0; c < C_CLS; ++c)
        val[c] = *(const f2*)(base + (size_t)c * HW);

#pragma unroll
    for (int j = 0; j < 2; ++j) {
        // first-max argmax (matches jnp.argmax) + max for softmax stability
        float m = val[0][j];
        int   am = 0;
#pragma unroll
        for (int c = 1; c < C_CLS; ++c) {
            float xv = val[c][j];
            if (xv > m) { m = xv; am = c; }
        }
        float l = 0.0f, q = 0.0f;
#pragma unroll
        for (int c = 0; c < C_CLS; ++c) {
            float e = __expf(val[c][j] - m);
            l += e;
            q += e * e;
        }
        float s = q * __builtin_amdgcn_rcpf(l * l);   // sum(prob^2)
        atomicAdd(&s_sum[am], s);
        atomicAdd(&s_cnt[am], 1.0f);                  // exact: int-valued < 2^24
    }

    __syncthreads();
    if (t < C_CLS) {
        atomicAdd(sum_slot(ws, t), s_sum[t]);
        atomicAdd(cnt_slot(ws, t), s_cnt[t]);
    }
    __syncthreads();                       // drains this block's global atomics
    if (t == 0) {
        __threadfence();                   // publish before taking a ticket
        unsigned int old = atomicAdd(ticket, 1u);
        s_last = (old == NBLK - 1) ? 1u : 0u;
    }
    __syncthreads();

    if (s_last && t < 64) {                // wave 0 of the last-done block
        float vsum = 0.0f;
        if (t < C_CLS) {
            float cnt = __hip_atomic_load(cnt_slot(ws, t), __ATOMIC_RELAXED,
                                          __HIP_MEMORY_SCOPE_AGENT);
            float sum = __hip_atomic_load(sum_slot(ws, t), __ATOMIC_RELAXED,
                                          __HIP_MEMORY_SCOPE_AGENT);
            const float scale = powf((float)NPIX, 1.0f - IW);  // Np^0.8
            float den = fmaxf(powf(cnt, IW) * scale, 1.0f);
            vsum = sum / den;
        }
#pragma unroll
        for (int off = 32; off > 0; off >>= 1)
            vsum += __shfl_down(vsum, off);
        if (t == 0)
            out[0] = -vsum / (float)(N_IMG * C_CLS);
    }
}

extern "C" void kernel_launch(void* const* d_in, const int* in_sizes, int n_in,
                              void* d_out, int out_size, void* d_ws, size_t ws_size,
                              hipStream_t stream) {
    const float* x = (const float*)d_in[0];
    float* out = (float*)d_out;
    float* ws  = (float*)d_ws;
    unsigned int* ticket = (unsigned int*)(ws + 2 * C_CLS * SLOT);

    zero_ws<<<1, 1024, 0, stream>>>((unsigned int*)d_ws);
    main_pass<<<NBLK, 256, 0, stream>>>(x, ws, ticket, out);
}

// Round 4
// 264.347 us; speedup vs baseline: 1.5301x; 1.5301x over previous
//
#include <hip/hip_runtime.h>

// nw_out [N=4, C=19, H=512, W=1024] fp32; output: 1 fp32 scalar.
#define N_IMG 4
#define C_CLS 19
#define HW    (512 * 1024)          // per-channel plane (floats)
#define NPIX  (N_IMG * HW)          // 2,097,152 pixels
#define PXB   512                   // pixels per block tile
#define NBLK  (NPIX / PXB)          // 4096 blocks (1024 per image, no straddle)
#define IW    0.2f

typedef float f2 __attribute__((ext_vector_type(2)));

// Direct global->LDS DMA, 16 B/lane. LDS dest is wave-uniform base + lane*16.
// Zero VGPR cost -> all segment loads stay in flight (max MLP).
__device__ __forceinline__ void gload_lds16(const float* g, float* lds_base) {
    __builtin_amdgcn_global_load_lds(
        (__attribute__((address_space(1))) void*)g,
        (__attribute__((address_space(3))) void*)lds_base, 16, 0, 0);
}

// ---------------------------------------------------------------------------
// main_pass: block b stages a [19][512] fp32 tile via global_load_lds (38
// wave-DMAs of 1 KB, all outstanding), then per pixel: first-max argmax +
// sum(prob^2); per-class LDS bins; per-block partials to UNIQUE global slots
// (no atomics, no fences, no ws zeroing needed).
// ---------------------------------------------------------------------------
__global__ __launch_bounds__(256) void main_pass(const float* __restrict__ x,
                                                 float* __restrict__ part) {
    __shared__ float tile[C_CLS * PXB];          // 38 KB
    __shared__ float s_sum[C_CLS];
    __shared__ float s_cnt[C_CLS];
    const int t    = threadIdx.x;
    const int lane = t & 63;
    const int wave = t >> 6;
    if (t < C_CLS) { s_sum[t] = 0.0f; s_cnt[t] = 0.0f; }

    const int b = blockIdx.x;
    const int n = b >> 10;                       // 1024 blocks per image
    const float* ibase = x + (size_t)n * C_CLS * HW + (size_t)(b & 1023) * PXB;

    // 38 segments (channel c, half h): 1 KB each; wave w issues segments
    // s ≡ w (mod 4). Global addr per lane = seg + lane*16B; LDS base uniform.
    for (int s = wave; s < 2 * C_CLS; s += 4) {
        const int c = s >> 1, h = s & 1;
        gload_lds16(ibase + (size_t)c * HW + h * 256 + lane * 4,
                    tile + c * PXB + h * 256);
    }
    __syncthreads();   // waits vmcnt(0): all DMAs landed; s_sum init visible

    // Each thread: 2 pixels from LDS (ds_read_b64 per channel).
    const int p0 = 2 * t;
    f2 v[C_CLS];
#pragma unroll
    for (int c = 0; c < C_CLS; ++c)
        v[c] = *(const f2*)(tile + c * PXB + p0);

#pragma unroll
    for (int j = 0; j < 2; ++j) {
        float m = v[0][j];
        int   am = 0;
#pragma unroll
        for (int c = 1; c < C_CLS; ++c) {
            float xv = v[c][j];
            if (xv > m) { m = xv; am = c; }      // first-max, matches jnp.argmax
        }
        float l = 0.0f, q = 0.0f;
#pragma unroll
        for (int c = 0; c < C_CLS; ++c) {
            float e = __expf(v[c][j] - m);
            l += e;
            q += e * e;
        }
        float s = q * __builtin_amdgcn_rcpf(l * l);   // sum(prob^2)
        atomicAdd(&s_sum[am], s);
        atomicAdd(&s_cnt[am], 1.0f);             // exact: int-valued < 2^24
    }

    __syncthreads();
    if (t < C_CLS) {                             // unique slots: no atomics
        part[(size_t)t           * NBLK + b] = s_sum[t];
        part[(size_t)(C_CLS + t) * NBLK + b] = s_cnt[t];
    }
}

// ---------------------------------------------------------------------------
// finalize: one block reduces [38][4096] partials; den_c = max(cnt^0.2 *
// Np^0.8, 1); out = -sum_c(sum_c/den_c) / (N*C). Kernel boundary = coherent.
// ---------------------------------------------------------------------------
__global__ __launch_bounds__(1024) void finalize(const float* __restrict__ part,
                                                 float* __restrict__ out) {
    __shared__ float sval[2 * C_CLS];
    const int wave = threadIdx.x >> 6, lane = threadIdx.x & 63;

    for (int v = wave; v < 2 * C_CLS; v += 16) {
        const float* row = part + (size_t)v * NBLK;
        float a = 0.0f;
        for (int i = lane; i < NBLK; i += 64) a += row[i];
#pragma unroll
        for (int off = 32; off > 0; off >>= 1) a += __shfl_down(a, off);
        if (lane == 0) sval[v] = a;
    }
    __syncthreads();

    if (threadIdx.x < 64) {
        float vsum = 0.0f;
        if (threadIdx.x < C_CLS) {
            float sum = sval[threadIdx.x];
            float cnt = sval[C_CLS + threadIdx.x];
            const float scale = powf((float)NPIX, 1.0f - IW);  // Np^0.8
            float den = fmaxf(powf(cnt, IW) * scale, 1.0f);
            vsum = sum / den;
        }
#pragma unroll
        for (int off = 32; off > 0; off >>= 1) vsum += __shfl_down(vsum, off);
        if (threadIdx.x == 0)
            out[0] = -vsum / (float)(N_IMG * C_CLS);
    }
}

extern "C" void kernel_launch(void* const* d_in, const int* in_sizes, int n_in,
                              void* d_out, int out_size, void* d_ws, size_t ws_size,
                              hipStream_t stream) {
    const float* x = (const float*)d_in[0];
    float* out  = (float*)d_out;
    float* part = (float*)d_ws;      // [2*C_CLS][NBLK] fp32 = 1.2 MB < ws_size

    main_pass<<<NBLK, 256, 0, stream>>>(x, part);
    finalize<<<1, 1024, 0, stream>>>(part, out);
}

// Round 5
// 243.860 us; speedup vs baseline: 1.6586x; 1.0840x over previous
//
#include <hip/hip_runtime.h>

// nw_out [N=4, C=19, H=512, W=1024] fp32; output: 1 fp32 scalar.
#define N_IMG  4
#define C_CLS  19
#define HW     (512 * 1024)               // per-channel plane (floats), 2^19
#define NPIX   (N_IMG * HW)               // 2,097,152 pixels
#define NBLK   256                        // 1 block/CU (LDS-forced)
#define WAVES  4
#define CHUNK  256                        // px per wave-chunk = 1 KB per channel
#define NCHUNK (NPIX / (NBLK * WAVES * CHUNK))   // = 8 chunks per wave
#define IW     0.2f

typedef float f4 __attribute__((ext_vector_type(4)));

// Direct global->LDS DMA, 16 B/lane (64 lanes -> 1 KB = 256 floats).
__device__ __forceinline__ void gload_lds16(const float* g, float* lds) {
    __builtin_amdgcn_global_load_lds(
        (__attribute__((address_space(1))) void*)g,
        (__attribute__((address_space(3))) void*)lds, 16, 0, 0);
}

// gfx9 s_waitcnt immediate: vmcnt[3:0]=imm[3:0], vmcnt[5:4]=imm[15:14];
// expcnt=imm[6:4], lgkmcnt=imm[11:8] set to max = don't wait on them.
__host__ __device__ constexpr int vmcnt_imm(int n) {
    return (n & 15) | ((n >> 4) << 14) | (7 << 4) | (15 << 8);
}

// ---------------------------------------------------------------------------
// main_pass: per-WAVE double-buffered DMA pipeline, no barriers in hot loop.
// Wave w of block b owns 2048 contiguous pixels (8 chunks of 256). Pipeline:
// issue DMAs for chunk j+1 -> wait vmcnt(19) (chunk j landed, j+1 in flight)
// -> compute chunk j. Per-class sums/counts in lane-local registers.
// ---------------------------------------------------------------------------
__global__ __launch_bounds__(256, 1) void main_pass(const float* __restrict__ x,
                                                    float* __restrict__ part) {
    __shared__ float tile[WAVES][2][C_CLS][CHUNK];   // 152 KB -> 1 block/CU
    __shared__ float s_sum[C_CLS];
    __shared__ float s_cnt[C_CLS];
    const int t = threadIdx.x, lane = t & 63, wave = t >> 6;
    if (t < C_CLS) { s_sum[t] = 0.0f; s_cnt[t] = 0.0f; }
    __syncthreads();                      // once, before the pipeline starts

    const int b = blockIdx.x;
    const size_t wbase = (size_t)(b * WAVES + wave) * (NCHUNK * CHUNK); // pixel idx
    const int    n     = (int)(wbase >> 19);          // image (no straddle: 8192|2^19)
    const float* ib    = x + (size_t)n * C_CLS * HW + (wbase & (HW - 1));

    float asum[C_CLS], acnt[C_CLS];
#pragma unroll
    for (int c = 0; c < C_CLS; ++c) { asum[c] = 0.0f; acnt[c] = 0.0f; }

    // Prologue: DMA chunk 0 into buffer 0.
#pragma unroll
    for (int c = 0; c < C_CLS; ++c)
        gload_lds16(ib + (size_t)c * HW + lane * 4, &tile[wave][0][c][0]);

    for (int j = 0; j < NCHUNK; ++j) {
        const int cur = j & 1;
        if (j + 1 < NCHUNK) {
            const float* ibn = ib + (size_t)(j + 1) * CHUNK;
#pragma unroll
            for (int c = 0; c < C_CLS; ++c)
                gload_lds16(ibn + (size_t)c * HW + lane * 4,
                            &tile[wave][cur ^ 1][c][0]);
            __builtin_amdgcn_sched_barrier(0);        // pin issue before wait
            __builtin_amdgcn_s_waitcnt(vmcnt_imm(C_CLS)); // chunk j landed
        } else {
            __builtin_amdgcn_s_waitcnt(vmcnt_imm(0));
        }
        __builtin_amdgcn_sched_barrier(0);            // no ds_read above wait

        // 4 px per lane, all 19 channels (ds_read_b128, conflict-free).
        f4 v[C_CLS];
#pragma unroll
        for (int c = 0; c < C_CLS; ++c)
            v[c] = *(const f4*)&tile[wave][cur][c][lane * 4];

#pragma unroll
        for (int k = 0; k < 4; ++k) {
            float m = v[0][k];
            int   am = 0;
#pragma unroll
            for (int c = 1; c < C_CLS; ++c) {
                float xv = v[c][k];
                if (xv > m) { m = xv; am = c; }       // first-max = jnp.argmax
            }
            float l = 0.0f, q = 0.0f;
#pragma unroll
            for (int c = 0; c < C_CLS; ++c) {
                float e = __expf(v[c][k] - m);
                l += e;
                q += e * e;
            }
            float s = q * __builtin_amdgcn_rcpf(l * l);   // sum(prob^2)
#pragma unroll
            for (int c = 0; c < C_CLS; ++c) {             // lane-local bins
                bool h = (am == c);
                asum[c] += h ? s : 0.0f;
                acnt[c] += h ? 1.0f : 0.0f;
            }
        }
        __builtin_amdgcn_sched_barrier(0);            // keep loop stages apart
    }

    // Wave-reduce the 38 lane-local accumulators; one LDS atomic set per wave.
#pragma unroll
    for (int c = 0; c < C_CLS; ++c) {
        float a = asum[c], k = acnt[c];
        for (int off = 32; off > 0; off >>= 1) {
            a += __shfl_down(a, off);
            k += __shfl_down(k, off);
        }
        if (lane == 0) { atomicAdd(&s_sum[c], a); atomicAdd(&s_cnt[c], k); }
    }
    __syncthreads();
    if (t < C_CLS) {                                  // unique slots, no fences
        part[(size_t)t           * NBLK + b] = s_sum[t];
        part[(size_t)(C_CLS + t) * NBLK + b] = s_cnt[t];
    }
}

// ---------------------------------------------------------------------------
// finalize: one block reduces [38][256] partials; den_c = max(cnt^0.2 *
// Np^0.8, 1); out = -sum_c(sum_c/den_c) / (N*C).
// ---------------------------------------------------------------------------
__global__ __launch_bounds__(256) void finalize(const float* __restrict__ part,
                                                float* __restrict__ out) {
    __shared__ float sval[2 * C_CLS];
    const int wave = threadIdx.x >> 6, lane = threadIdx.x & 63;

    for (int v = wave; v < 2 * C_CLS; v += 4) {
        const float* row = part + (size_t)v * NBLK;
        float a = 0.0f;
        for (int i = lane; i < NBLK; i += 64) a += row[i];
#pragma unroll
        for (int off = 32; off > 0; off >>= 1) a += __shfl_down(a, off);
        if (lane == 0) sval[v] = a;
    }
    __syncthreads();

    if (threadIdx.x < 64) {
        float vsum = 0.0f;
        if (threadIdx.x < C_CLS) {
            float sum = sval[threadIdx.x];
            float cnt = sval[C_CLS + threadIdx.x];
            const float scale = powf((float)NPIX, 1.0f - IW);   // Np^0.8
            float den = fmaxf(powf(cnt, IW) * scale, 1.0f);
            vsum = sum / den;
        }
#pragma unroll
        for (int off = 32; off > 0; off >>= 1) vsum += __shfl_down(vsum, off);
        if (threadIdx.x == 0)
            out[0] = -vsum / (float)(N_IMG * C_CLS);
    }
}

extern "C" void kernel_launch(void* const* d_in, const int* in_sizes, int n_in,
                              void* d_out, int out_size, void* d_ws, size_t ws_size,
                              hipStream_t stream) {
    const float* x = (const float*)d_in[0];
    float* out  = (float*)d_out;
    float* part = (float*)d_ws;          // [2*C_CLS][NBLK] fp32 = 76 KB

    main_pass<<<NBLK, 256, 0, stream>>>(x, part);
    finalize<<<1, 256, 0, stream>>>(part, out);
}